// Round 12
// baseline (328.710 us; speedup 1.0000x reference)
//
#include <hip/hip_runtime.h>
#include <math.h>

static constexpr int B = 4, H = 160, W = 160;
static constexpr int HW = H * W;          // 25600
static constexpr int CHW = 64 * HW;       // 1638400
static constexpr int NELEM = B * CHW;     // 6553600

// padded grid for aspp GEMM view: 168x168 (halo 4) + guard slack
static constexpr int WP = 168;
static constexpr int HP = 168;
static constexpr int PHW = WP * HP;       // 28224
static constexpr int PGUARD = 704;        // front guard (>= 4*168+16)
static constexpr int PSTRIDE = 30720;     // per-b px stride
static constexpr int IMGOFS = PGUARD + 4 * WP + 4;  // = 1380, padded idx of (0,0)

typedef short bf16x8 __attribute__((ext_vector_type(8)));
typedef float f32x4 __attribute__((ext_vector_type(4)));

__device__ __forceinline__ float lrelu(float v) { return v >= 0.f ? v : 0.1f * v; }

__device__ __forceinline__ unsigned short f2bf(float f) {
  unsigned u = __float_as_uint(f);
  return (unsigned short)((u + 0x7FFFu + ((u >> 16) & 1u)) >> 16);  // RNE
}
__device__ __forceinline__ float bf2f(short u) {
  return __uint_as_float(((unsigned)(unsigned short)u) << 16);
}

__device__ __forceinline__ void glds16(const void* g, void* l) {
  __builtin_amdgcn_global_load_lds(
      (const __attribute__((address_space(1))) void*)g,
      (__attribute__((address_space(3))) void*)l, 16, 0, 0);
}

// ---------------------------------------------------------------------------
// Weight transforms + zero-fill of the padded input buffer (margins must be 0).
// ---------------------------------------------------------------------------
__global__ __launch_bounds__(256) void k_transform(
    const float* __restrict__ w01, const float* __restrict__ dw,
    const float* __restrict__ arw, const float* __restrict__ a1w,
    const float* __restrict__ a2w, const float* __restrict__ a3w,
    float* __restrict__ wt01, unsigned short* __restrict__ wb_bf,
    unsigned short* __restrict__ wd_bf, unsigned short* __restrict__ arw_bf,
    unsigned short* __restrict__ off0p) {
  int i = blockIdx.x * 256 + threadIdx.x;  // 0 .. 167935
  uint4* zp = (uint4*)off0p;
#pragma unroll
  for (int j = 0; j < 6; ++j) {
    unsigned u = (unsigned)i + (unsigned)j * 167936u;
    if (u < 983040u) zp[u] = make_uint4(0u, 0u, 0u, 0u);
  }
  if (i < 8192) {
    int ci = i >> 6, o = i & 63;
    wt01[i] = w01[o * 128 + ci];
  } else if (i < 118784) {
    int j = i - 8192;
    int ci = j & 63, co = (j >> 6) & 63;
    int kk = j >> 12;              // dsel*9 + k, 0..26
    int dsel = kk / 9; kk -= dsel * 9;
    const float* src = dsel == 0 ? a1w : dsel == 1 ? a2w : a3w;
    wb_bf[j] = f2bf(src[(co * 64 + ci) * 9 + kk]);
  } else if (i < 155648) {
    int j = i - 118784;
    int ci = j & 63, co = (j >> 6) & 63, k = j >> 12;  // k 0..8
    wd_bf[j] = f2bf(dw[(co * 64 + ci) * 9 + k]);
  } else if (i < 167936) {
    int j = i - 155648;
    arw_bf[j] = f2bf(arw[j]);  // already [o][cp]
  }
}

// ---------------------------------------------------------------------------
// Kernel A: 1x1 conv concat(aux,ref) 128->64 + bias + lrelu.
// Emits fp32 channel-major off0, bf16 PADDED pos-major off0p[ppos][ci], AND
// bf16 pos-major x_bf[pos][ci] (aux transpose, from the same LDS staging).
// grid: B*HW/64 = 1600
// ---------------------------------------------------------------------------
__global__ __launch_bounds__(256) void k_conv1x1_in(
    const float* __restrict__ aux, const float* __restrict__ ref,
    const float* __restrict__ wt01, const float* __restrict__ b01,
    float* __restrict__ out, unsigned short* __restrict__ off0p,
    unsigned short* __restrict__ x_bf) {
  __shared__ float s[128 * 64];  // 32 KB  s[ci*64+p]
  int pos0 = blockIdx.x * 64;
  int b = pos0 / HW;
  int hw0 = pos0 - b * HW;
  int tid = threadIdx.x;
  for (int i = tid; i < 8192; i += 256) {
    int ci = i >> 6, p = i & 63;
    const float* src = (ci < 64) ? (aux + b * CHW + ci * HW)
                                 : (ref + b * CHW + (ci - 64) * HW);
    s[i] = src[hw0 + p];
  }
  __syncthreads();
  int p = tid & 63;
  int g = __builtin_amdgcn_readfirstlane(tid >> 6);
  const float* wp = wt01 + g * 16;
  float acc[16];
#pragma unroll
  for (int j = 0; j < 16; ++j) acc[j] = 0.f;
#pragma unroll 4
  for (int ci = 0; ci < 128; ++ci) {
    float sv = s[ci * 64 + p];
    const float* wrow = wp + ci * 64;  // uniform, o-contiguous -> s_loads
#pragma unroll
    for (int j = 0; j < 16; ++j) acc[j] += sv * wrow[j];
  }
  const float* bb = b01 + g * 16;
  int obase = (b * 64 + g * 16) * HW + hw0 + p;
  unsigned short tb[16];
#pragma unroll
  for (int j = 0; j < 16; ++j) {
    float v = lrelu(acc[j] + bb[j]);
    out[obase + j * HW] = v;
    tb[j] = f2bf(v);
  }
  int hw = hw0 + p;
  int h = hw / W, w = hw - h * W;
  unsigned short* dst =
      off0p + ((size_t)b * PSTRIDE + IMGOFS + h * WP + w) * 64 + g * 16;
  *(uint4*)dst = *(const uint4*)&tb[0];
  *(uint4*)(dst + 8) = *(const uint4*)&tb[8];
  // x_bf: aux transpose from the staged LDS (rows 0..63 are aux)
  unsigned short xb[16];
#pragma unroll
  for (int j = 0; j < 16; ++j) xb[j] = f2bf(s[(g * 16 + j) * 64 + p]);
  unsigned short* xdst = x_bf + ((size_t)(b * HW + hw0 + p)) * 64 + g * 16;
  *(uint4*)xdst = *(const uint4*)&xb[0];
  *(uint4*)(xdst + 8) = *(const uint4*)&xb[8];
}

// ---------------------------------------------------------------------------
// Kernel B v6: padded-GEMM aspp + TRUE counted-vmcnt pipeline (T4).
// v5's __syncthreads() emitted s_waitcnt vmcnt(0) at every barrier -> the
// STAGE(next) prefetch was drained before COMPUTE began (the m97 stall).
// Now: raw s_barrier + per-wave counted s_waitcnt vmcnt(9) -- each wave
// issues 9 glds per stage; waiting vmcnt(9) after issuing the NEXT stage's
// 9 leaves them in flight while guaranteeing the current buffer's 9 (the
// oldest) completed. bfrag global loads inflate the outstanding count only
// conservatively (over-wait, never under-wait). lgkmcnt(0) before barriers
// that precede a buffer overwrite; sched_barrier(0) fences (rule #18).
// ---------------------------------------------------------------------------
__global__ __launch_bounds__(256) void k_aspp3_mfma(
    const unsigned short* __restrict__ off0p,
    const unsigned short* __restrict__ wb_bf,
    const float* __restrict__ a1b, const float* __restrict__ a2b,
    const float* __restrict__ a3b, unsigned short* __restrict__ r_bf) {
  __shared__ unsigned short sa[2][288 * 64];  // 2 x 36864 B
  int tid = threadIdx.x;
  int lane = tid & 63, wid = tid >> 6;
  int m = lane & 15, q = lane >> 4;

  // bijective XCD swizzle for nwg=1332 (q=166, r=4)
  int p0 = blockIdx.x;
  int xcd = p0 & 7, ii = p0 >> 3;
  int base = xcd < 4 ? xcd * 167 : 668 + (xcd - 4) * 166;
  int lid = base + ii;
  int dsel = lid % 3;
  int tj = lid / 3;
  int b = tj / 111;
  int tile = tj - b * 111;
  int pos0 = tile * 256;
  const int d = 1 << dsel;
  const unsigned short* pb = off0p + (size_t)b * PSTRIDE * 64;
  const float* bias = dsel == 0 ? a1b : dsel == 1 ? a2b : a3b;

  f32x4 acc[4][4] = {};

  auto STAGE = [&](int buf, int ky) {
    const char* src =
        (const char*)(pb + (size_t)(PGUARD + pos0 + (ky - 1) * d * WP - 16) * 64);
    char* dstb = (char*)&sa[buf][0];
#pragma unroll
    for (int r = 0; r < 9; ++r) {
      int X = r * 4096 + tid * 16;       // byte offset in window (linear dest)
      int row = X >> 7;                  // px index in window
      int Xs = X ^ ((row & 7) << 4);     // source permutation = read permutation
      glds16(src + Xs, dstb + X);
    }
  };
  auto COMPUTE = [&](int buf, int ky) {
    const char* sb = (const char*)&sa[buf][0];
    __builtin_amdgcn_s_setprio(1);
#pragma unroll
    for (int kx = 0; kx < 3; ++kx) {
      const unsigned short* wk = wb_bf + (dsel * 9 + ky * 3 + kx) * 4096;
      int px0 = 16 + (kx - 1) * d + wid * 64;  // window-relative px, this wave
#pragma unroll
      for (int kc = 0; kc < 2; ++kc) {
        bf16x8 bfrag[4];
#pragma unroll
        for (int t = 0; t < 4; ++t)
          bfrag[t] = *(const bf16x8*)(wk + (t * 16 + m) * 64 + kc * 32 + q * 8);
#pragma unroll
        for (int mt = 0; mt < 4; ++mt) {
          int px = px0 + mt * 16 + m;
          int byteoff = px * 128 + ((kc * 64 + q * 16) ^ ((px & 7) << 4));
          bf16x8 afrag = *(const bf16x8*)(sb + byteoff);
#pragma unroll
          for (int t = 0; t < 4; ++t)
            acc[mt][t] = __builtin_amdgcn_mfma_f32_16x16x32_bf16(
                afrag, bfrag[t], acc[mt][t], 0, 0, 0);
        }
      }
    }
    __builtin_amdgcn_s_setprio(0);
  };

  STAGE(0, 0);
  STAGE(1, 1);                 // 18 glds in flight per wave
  asm volatile("s_waitcnt vmcnt(9)" ::: "memory");   // buf0's 9 (oldest) done
  __builtin_amdgcn_s_barrier();
  __builtin_amdgcn_sched_barrier(0);
  COMPUTE(0, 0);               // buf1's 9 stay in flight under these MFMAs
  asm volatile("s_waitcnt lgkmcnt(0)" ::: "memory"); // this wave's buf0 reads done
  __builtin_amdgcn_s_barrier();                      // all waves' reads done
  __builtin_amdgcn_sched_barrier(0);
  STAGE(0, 2);                 // overwrite buf0
  asm volatile("s_waitcnt vmcnt(9)" ::: "memory");   // buf1 staged (conservative)
  __builtin_amdgcn_s_barrier();
  __builtin_amdgcn_sched_barrier(0);
  COMPUTE(1, 1);               // buf0's r2 loads in flight under these MFMAs
  asm volatile("s_waitcnt vmcnt(0)" ::: "memory");   // buf0 (r2) staged
  __builtin_amdgcn_s_barrier();
  __builtin_amdgcn_sched_barrier(0);
  COMPUTE(0, 2);

  // epilogue: bias + lrelu, pack bf16 via LDS (stride 68: v3-proven 0-conflict)
  asm volatile("s_waitcnt lgkmcnt(0)" ::: "memory"); // all reads done before
  __builtin_amdgcn_s_barrier();                      // overwriting sa[0]
  __builtin_amdgcn_sched_barrier(0);
  unsigned short* epb = &sa[0][0];  // ep[pix*68 + co], 34816 B
#pragma unroll
  for (int t = 0; t < 4; ++t) {
    float bi = bias[t * 16 + m];
#pragma unroll
    for (int mt = 0; mt < 4; ++mt)
#pragma unroll
      for (int r = 0; r < 4; ++r)  // D: col=co (m), row=q*4+r (pixel)
        epb[(wid * 64 + mt * 16 + q * 4 + r) * 68 + t * 16 + m] =
            f2bf(lrelu(acc[mt][t][r] + bi));
  }
  __syncthreads();
  {
    int qa = pos0 + tid;  // padded position of this thread's pixel
    int pr = qa / WP, pc = qa - pr * WP;
    if (pr >= 4 && pr < 164 && pc >= 4 && pc < 164) {
      int hw = (pr - 4) * W + (pc - 4);
      unsigned short* dst = r_bf + ((size_t)(b * HW + hw)) * 192 + dsel * 64;
      const unsigned short* s2 = epb + tid * 68;
#pragma unroll
      for (int c = 0; c < 8; ++c)
        *(uint4*)(dst + c * 8) = *(const uint4*)(s2 + c * 8);
    }
  }
}

// ---------------------------------------------------------------------------
// Kernel C: MFMA merge 192->64 (+bias+residual) then offset head 64->18.
// grid: B*HW/64 = 1600
// ---------------------------------------------------------------------------
__global__ __launch_bounds__(256) void k_merge_head_mfma(
    const unsigned short* __restrict__ r_bf, const float* __restrict__ off0,
    const unsigned short* __restrict__ arw_bf, const float* __restrict__ arb,
    const float* __restrict__ w02, const float* __restrict__ b02,
    float* __restrict__ offs) {
  __shared__ unsigned short sa[64 * 200];  // 25600 B; reused as float ep[64*65]
  int pos0 = blockIdx.x * 64;
  int b = pos0 / HW;
  int hw0 = pos0 - b * HW;
  int tid = threadIdx.x;
  const unsigned short* gsrc = r_bf + (size_t)(b * HW + hw0) * 192;
  for (int i = tid; i < 1536; i += 256) {
    int pos = i / 24, c8 = i - pos * 24;
    *(uint4*)(sa + pos * 200 + c8 * 8) = *(const uint4*)(gsrc + i * 8);
  }
  __syncthreads();
  int lane = tid & 63, wid = tid >> 6;
  int m = lane & 15, q = lane >> 4;
  f32x4 acc[4] = {};
#pragma unroll
  for (int kc = 0; kc < 6; ++kc) {
    bf16x8 bfrag = *(const bf16x8*)(arw_bf + (wid * 16 + m) * 192 + kc * 32 + q * 8);
#pragma unroll
    for (int mt = 0; mt < 4; ++mt) {
      bf16x8 afrag = *(const bf16x8*)(sa + (mt * 16 + m) * 200 + kc * 32 + q * 8);
      acc[mt] = __builtin_amdgcn_mfma_f32_16x16x32_bf16(afrag, bfrag, acc[mt],
                                                        0, 0, 0);
    }
  }
  __syncthreads();  // all afrag reads done before overwriting sa
  float* ep = (float*)sa;  // ep[pos*65 + co]
  int co = wid * 16 + m;
  float bi = arb[co];
  const float* resrow = off0 + (size_t)(b * 64 + co) * HW + hw0;
#pragma unroll
  for (int mt = 0; mt < 4; ++mt)
#pragma unroll
    for (int r = 0; r < 4; ++r) {
      int pos = mt * 16 + q * 4 + r;  // D: col=co, row=pos
      ep[pos * 65 + co] = acc[mt][r] + bi + resrow[pos];
    }
  __syncthreads();
  for (int i = tid; i < 1152; i += 256) {
    int t = i >> 6, p = i & 63;
    const float* w2 = w02 + t * 64;  // t wave-uniform -> s_loads
    float o = b02[t];
#pragma unroll 8
    for (int c = 0; c < 64; ++c) o += ep[p * 65 + c] * w2[c];
    offs[(b * 18 + t) * HW + hw0 + p] = o;
  }
}

// ---------------------------------------------------------------------------
// Kernel E v8: tap-paired LDS sampling + MFMA (R11 passing version, unchanged)
// grid: 1600
// ---------------------------------------------------------------------------
__global__ __launch_bounds__(256) void k_deform_mfma(
    const unsigned short* __restrict__ x_bf, const float* __restrict__ offs,
    const unsigned short* __restrict__ wd_bf, const float* __restrict__ db,
    float* __restrict__ out) {
  __shared__ unsigned short sb[2][2][64 * 64];  // 2 bufs x 2 taps x 8 KB = 32 KB
  int blk = (blockIdx.x & 7) * 200 + (blockIdx.x >> 3);  // XCD slab swizzle
  int pos0 = blk * 64;
  int b = pos0 / HW;
  int hw0 = pos0 - b * HW;
  int tid = threadIdx.x;
  int lane = tid & 63, wid = tid >> 6;
  int m = lane & 15, q = lane >> 4;
  int p = lane;          // sampling position
  int cg = wid;          // sampling ci-group (16 ci)
  int hw = hw0 + p;
  int h = hw / W, wv = hw - h * W;
  const unsigned short* xbase = x_bf + (size_t)b * HW * 64;
  const float* ob = offs + b * 18 * HW + hw;
  float offv[18];
#pragma unroll
  for (int j = 0; j < 18; ++j) offv[j] = ob[j * HW];
  f32x4 acc[4] = {};

  // gather + bilinear blend + swizzled ds_write of tap k into dstbase
  auto SAMPLE = [&](int k, unsigned short* dstbase) {
    const int ky = k / 3, kx = k - ky * 3;
    float py = offv[2 * k] + (float)(h - 1 + ky);
    float pxf = offv[2 * k + 1] + (float)(wv - 1 + kx);
    float fy = floorf(py), fx = floorf(pxf);
    int iy0 = (int)fy, ix0 = (int)fx;
    float wy = py - fy, wx = pxf - fx;
    int iy1 = iy0 + 1, ix1 = ix0 + 1;
    float vy0 = (iy0 >= 0 && iy0 < H) ? 1.f : 0.f;
    float vy1 = (iy1 >= 0 && iy1 < H) ? 1.f : 0.f;
    float vx0 = (ix0 >= 0 && ix0 < W) ? 1.f : 0.f;
    float vx1 = (ix1 >= 0 && ix1 < W) ? 1.f : 0.f;
    int cy0 = min(max(iy0, 0), H - 1), cy1 = min(max(iy1, 0), H - 1);
    int cx0 = min(max(ix0, 0), W - 1), cx1 = min(max(ix1, 0), W - 1);
    float c00 = vy0 * vx0 * (1.f - wy) * (1.f - wx);
    float c01 = vy0 * vx1 * (1.f - wy) * wx;
    float c10 = vy1 * vx0 * wy * (1.f - wx);
    float c11 = vy1 * vx1 * wy * wx;
    const unsigned short* p00 = xbase + (size_t)(cy0 * W + cx0) * 64 + cg * 16;
    const unsigned short* p01 = xbase + (size_t)(cy0 * W + cx1) * 64 + cg * 16;
    const unsigned short* p10 = xbase + (size_t)(cy1 * W + cx0) * 64 + cg * 16;
    const unsigned short* p11 = xbase + (size_t)(cy1 * W + cx1) * 64 + cg * 16;
    unsigned tw0[4], tw1[4];
#pragma unroll
    for (int c2 = 0; c2 < 2; ++c2) {
      bf16x8 v00 = *(const bf16x8*)(p00 + c2 * 8);
      bf16x8 v01 = *(const bf16x8*)(p01 + c2 * 8);
      bf16x8 v10 = *(const bf16x8*)(p10 + c2 * 8);
      bf16x8 v11 = *(const bf16x8*)(p11 + c2 * 8);
      unsigned* tw = c2 ? tw1 : tw0;
#pragma unroll
      for (int jj = 0; jj < 4; ++jj) {
        float s0 = c00 * bf2f(v00[2 * jj]) + c01 * bf2f(v01[2 * jj]) +
                   c10 * bf2f(v10[2 * jj]) + c11 * bf2f(v11[2 * jj]);
        float s1 = c00 * bf2f(v00[2 * jj + 1]) + c01 * bf2f(v01[2 * jj + 1]) +
                   c10 * bf2f(v10[2 * jj + 1]) + c11 * bf2f(v11[2 * jj + 1]);
        asm("v_cvt_pk_bf16_f32 %0, %1, %2" : "=v"(tw[jj]) : "v"(s0), "v"(s1));
      }
    }
    char* wbase = (char*)dstbase + p * 128;
    *(uint4*)(wbase + ((cg * 32) ^ ((p & 7) << 4))) = *(const uint4*)&tw0[0];
    *(uint4*)(wbase + ((cg * 32 + 16) ^ ((p & 7) << 4))) = *(const uint4*)&tw1[0];
  };
  auto GEMM_TAP = [&](int k, const unsigned short* basep) {
#pragma unroll
    for (int kc = 0; kc < 2; ++kc) {
      bf16x8 bfrag =
          *(const bf16x8*)(wd_bf + (k * 64 + wid * 16 + m) * 64 + kc * 32 + q * 8);
#pragma unroll
      for (int mt = 0; mt < 4; ++mt) {
        int row = mt * 16 + m;
        int off = (kc * 64 + q * 16) ^ ((row & 7) << 4);  // same involution
        bf16x8 afrag = *(const bf16x8*)((const char*)basep + row * 128 + off);
        acc[mt] = __builtin_amdgcn_mfma_f32_16x16x32_bf16(afrag, bfrag, acc[mt],
                                                          0, 0, 0);
      }
    }
  };

#pragma unroll
  for (int r = 0; r < 4; ++r) {
    SAMPLE(2 * r, &sb[r & 1][0][0]);
    SAMPLE(2 * r + 1, &sb[r & 1][1][0]);
    __builtin_amdgcn_sched_barrier(0);
    asm volatile("s_waitcnt lgkmcnt(0)" ::: "memory");
    __builtin_amdgcn_s_barrier();
    __builtin_amdgcn_sched_barrier(0);
    __builtin_amdgcn_s_setprio(1);
    GEMM_TAP(2 * r, &sb[r & 1][0][0]);
    GEMM_TAP(2 * r + 1, &sb[r & 1][1][0]);
    __builtin_amdgcn_s_setprio(0);
  }
  // tap 8 (round 4, buf 0 half 0 -- last read at round 2; round 3's barrier
  // separates those reads from these writes, same spacing as the loop)
  SAMPLE(8, &sb[0][0][0]);
  __builtin_amdgcn_sched_barrier(0);
  asm volatile("s_waitcnt lgkmcnt(0)" ::: "memory");
  __builtin_amdgcn_s_barrier();
  __builtin_amdgcn_sched_barrier(0);
  __builtin_amdgcn_s_setprio(1);
  GEMM_TAP(8, &sb[0][0][0]);
  __builtin_amdgcn_s_setprio(0);

  int co = wid * 16 + m;
  float bias = db[co];
  size_t orow = (size_t)(b * 64 + co) * HW + hw0;
#pragma unroll
  for (int mt = 0; mt < 4; ++mt)
#pragma unroll
    for (int r = 0; r < 4; ++r)
      out[orow + mt * 16 + q * 4 + r] = acc[mt][r] + bias;  // D: col=co, row=pos
}

// ---------------------------------------------------------------------------
extern "C" void kernel_launch(void* const* d_in, const int* in_sizes, int n_in,
                              void* d_out, int out_size, void* d_ws, size_t ws_size,
                              hipStream_t stream) {
  const float* aux = (const float*)d_in[0];
  const float* ref = (const float*)d_in[1];
  const float* w01 = (const float*)d_in[2];
  const float* b01 = (const float*)d_in[3];
  const float* a1w = (const float*)d_in[4];
  const float* a1b = (const float*)d_in[5];
  const float* a2w = (const float*)d_in[6];
  const float* a2b = (const float*)d_in[7];
  const float* a3w = (const float*)d_in[8];
  const float* a3b = (const float*)d_in[9];
  const float* arw = (const float*)d_in[10];
  const float* arb = (const float*)d_in[11];
  const float* w02 = (const float*)d_in[12];
  const float* b02 = (const float*)d_in[13];
  const float* dw  = (const float*)d_in[14];
  const float* db  = (const float*)d_in[15];
  float* out = (float*)d_out;

  float* off0 = (float*)d_ws;                        // [B,64,H,W] fp32
  float* offs = off0 + NELEM;                        // [B,18,H,W] fp32
  float* wt01 = offs + B * 18 * HW;                  // 8192 f32
  unsigned short* off0p = (unsigned short*)(wt01 + 8192);    // [B,PSTRIDE,64] bf16
  unsigned short* x_bf   = off0p + (size_t)B * PSTRIDE * 64; // [B,HW,64] bf16
  unsigned short* wb_bf  = x_bf + (size_t)NELEM;             // 110592 bf16
  unsigned short* wd_bf  = wb_bf + 110592;                   // 36864 bf16
  unsigned short* arw_bf = wd_bf + 36864;                    // 12288 bf16
  unsigned short* r_bf   = arw_bf + 12288;           // [B,HW,192] bf16

  k_transform<<<656, 256, 0, stream>>>(w01, dw, arw, a1w, a2w, a3w,
                                       wt01, wb_bf, wd_bf, arw_bf, off0p);
  k_conv1x1_in<<<B * HW / 64, 256, 0, stream>>>(aux, ref, wt01, b01, off0,
                                                off0p, x_bf);
  k_aspp3_mfma<<<1332, 256, 0, stream>>>(off0p, wb_bf, a1b, a2b, a3b, r_bf);
  k_merge_head_mfma<<<B * HW / 64, 256, 0, stream>>>(
      r_bf, off0, arw_bf, arb, w02, b02, offs);
  k_deform_mfma<<<B * HW / 64, 256, 0, stream>>>(x_bf, offs, wd_bf, db, out);
}

// Round 13
// 320.767 us; speedup vs baseline: 1.0248x; 1.0248x over previous
//
#include <hip/hip_runtime.h>
#include <math.h>

static constexpr int B = 4, H = 160, W = 160;
static constexpr int HW = H * W;          // 25600
static constexpr int CHW = 64 * HW;       // 1638400
static constexpr int NELEM = B * CHW;     // 6553600

// padded grid for aspp GEMM view: 168x168 (halo 4) + guard slack
static constexpr int WP = 168;
static constexpr int HP = 168;
static constexpr int PHW = WP * HP;       // 28224
static constexpr int PGUARD = 704;        // front guard (>= 4*168+16)
static constexpr int PSTRIDE = 30720;     // per-b px stride
static constexpr int IMGOFS = PGUARD + 4 * WP + 4;  // = 1380, padded idx of (0,0)

typedef short bf16x8 __attribute__((ext_vector_type(8)));
typedef float f32x4 __attribute__((ext_vector_type(4)));

__device__ __forceinline__ float lrelu(float v) { return v >= 0.f ? v : 0.1f * v; }

__device__ __forceinline__ unsigned short f2bf(float f) {
  unsigned u = __float_as_uint(f);
  return (unsigned short)((u + 0x7FFFu + ((u >> 16) & 1u)) >> 16);  // RNE
}
__device__ __forceinline__ float bf2f(short u) {
  return __uint_as_float(((unsigned)(unsigned short)u) << 16);
}

__device__ __forceinline__ void glds16(const void* g, void* l) {
  __builtin_amdgcn_global_load_lds(
      (const __attribute__((address_space(1))) void*)g,
      (__attribute__((address_space(3))) void*)l, 16, 0, 0);
}

// ---------------------------------------------------------------------------
// Weight transforms + zero-fill of the padded input buffer (margins must be 0).
// ---------------------------------------------------------------------------
__global__ __launch_bounds__(256) void k_transform(
    const float* __restrict__ w01, const float* __restrict__ dw,
    const float* __restrict__ arw, const float* __restrict__ a1w,
    const float* __restrict__ a2w, const float* __restrict__ a3w,
    float* __restrict__ wt01, unsigned short* __restrict__ wb_bf,
    unsigned short* __restrict__ wd_bf, unsigned short* __restrict__ arw_bf,
    unsigned short* __restrict__ off0p) {
  int i = blockIdx.x * 256 + threadIdx.x;  // 0 .. 167935
  uint4* zp = (uint4*)off0p;
#pragma unroll
  for (int j = 0; j < 6; ++j) {
    unsigned u = (unsigned)i + (unsigned)j * 167936u;
    if (u < 983040u) zp[u] = make_uint4(0u, 0u, 0u, 0u);
  }
  if (i < 8192) {
    int ci = i >> 6, o = i & 63;
    wt01[i] = w01[o * 128 + ci];
  } else if (i < 118784) {
    int j = i - 8192;
    int ci = j & 63, co = (j >> 6) & 63;
    int kk = j >> 12;              // dsel*9 + k, 0..26
    int dsel = kk / 9; kk -= dsel * 9;
    const float* src = dsel == 0 ? a1w : dsel == 1 ? a2w : a3w;
    wb_bf[j] = f2bf(src[(co * 64 + ci) * 9 + kk]);
  } else if (i < 155648) {
    int j = i - 118784;
    int ci = j & 63, co = (j >> 6) & 63, k = j >> 12;  // k 0..8
    wd_bf[j] = f2bf(dw[(co * 64 + ci) * 9 + k]);
  } else if (i < 167936) {
    int j = i - 155648;
    arw_bf[j] = f2bf(arw[j]);  // already [o][cp]
  }
}

// ---------------------------------------------------------------------------
// Kernel A: 1x1 conv concat(aux,ref) 128->64 + bias + lrelu.
// Emits fp32 channel-major off0, bf16 PADDED pos-major off0p[ppos][ci], AND
// bf16 pos-major x_bf[pos][ci] (aux transpose, from the same LDS staging).
// grid: B*HW/64 = 1600
// ---------------------------------------------------------------------------
__global__ __launch_bounds__(256) void k_conv1x1_in(
    const float* __restrict__ aux, const float* __restrict__ ref,
    const float* __restrict__ wt01, const float* __restrict__ b01,
    float* __restrict__ out, unsigned short* __restrict__ off0p,
    unsigned short* __restrict__ x_bf) {
  __shared__ float s[128 * 64];  // 32 KB  s[ci*64+p]
  int pos0 = blockIdx.x * 64;
  int b = pos0 / HW;
  int hw0 = pos0 - b * HW;
  int tid = threadIdx.x;
  for (int i = tid; i < 8192; i += 256) {
    int ci = i >> 6, p = i & 63;
    const float* src = (ci < 64) ? (aux + b * CHW + ci * HW)
                                 : (ref + b * CHW + (ci - 64) * HW);
    s[i] = src[hw0 + p];
  }
  __syncthreads();
  int p = tid & 63;
  int g = __builtin_amdgcn_readfirstlane(tid >> 6);
  const float* wp = wt01 + g * 16;
  float acc[16];
#pragma unroll
  for (int j = 0; j < 16; ++j) acc[j] = 0.f;
#pragma unroll 4
  for (int ci = 0; ci < 128; ++ci) {
    float sv = s[ci * 64 + p];
    const float* wrow = wp + ci * 64;  // uniform, o-contiguous -> s_loads
#pragma unroll
    for (int j = 0; j < 16; ++j) acc[j] += sv * wrow[j];
  }
  const float* bb = b01 + g * 16;
  int obase = (b * 64 + g * 16) * HW + hw0 + p;
  unsigned short tb[16];
#pragma unroll
  for (int j = 0; j < 16; ++j) {
    float v = lrelu(acc[j] + bb[j]);
    out[obase + j * HW] = v;
    tb[j] = f2bf(v);
  }
  int hw = hw0 + p;
  int h = hw / W, w = hw - h * W;
  unsigned short* dst =
      off0p + ((size_t)b * PSTRIDE + IMGOFS + h * WP + w) * 64 + g * 16;
  *(uint4*)dst = *(const uint4*)&tb[0];
  *(uint4*)(dst + 8) = *(const uint4*)&tb[8];
  // x_bf: aux transpose from the staged LDS (rows 0..63 are aux)
  unsigned short xb[16];
#pragma unroll
  for (int j = 0; j < 16; ++j) xb[j] = f2bf(s[(g * 16 + j) * 64 + p]);
  unsigned short* xdst = x_bf + ((size_t)(b * HW + hw0 + p)) * 64 + g * 16;
  *(uint4*)xdst = *(const uint4*)&xb[0];
  *(uint4*)(xdst + 8) = *(const uint4*)&xb[8];
}

// ---------------------------------------------------------------------------
// Kernel B v5: padded-GEMM aspp, row-union staging + 2-phase pipeline + swz.
// (R11 best-measured version: __syncthreads skeleton + T5 setprio)
// ---------------------------------------------------------------------------
__global__ __launch_bounds__(256) void k_aspp3_mfma(
    const unsigned short* __restrict__ off0p,
    const unsigned short* __restrict__ wb_bf,
    const float* __restrict__ a1b, const float* __restrict__ a2b,
    const float* __restrict__ a3b, unsigned short* __restrict__ r_bf) {
  __shared__ unsigned short sa[2][288 * 64];  // 2 x 36864 B
  int tid = threadIdx.x;
  int lane = tid & 63, wid = tid >> 6;
  int m = lane & 15, q = lane >> 4;

  // bijective XCD swizzle for nwg=1332 (q=166, r=4)
  int p0 = blockIdx.x;
  int xcd = p0 & 7, ii = p0 >> 3;
  int base = xcd < 4 ? xcd * 167 : 668 + (xcd - 4) * 166;
  int lid = base + ii;
  int dsel = lid % 3;
  int tj = lid / 3;
  int b = tj / 111;
  int tile = tj - b * 111;
  int pos0 = tile * 256;
  const int d = 1 << dsel;
  const unsigned short* pb = off0p + (size_t)b * PSTRIDE * 64;
  const float* bias = dsel == 0 ? a1b : dsel == 1 ? a2b : a3b;

  f32x4 acc[4][4] = {};

  auto STAGE = [&](int buf, int ky) {
    const char* src =
        (const char*)(pb + (size_t)(PGUARD + pos0 + (ky - 1) * d * WP - 16) * 64);
    char* dstb = (char*)&sa[buf][0];
#pragma unroll
    for (int r = 0; r < 9; ++r) {
      int X = r * 4096 + tid * 16;       // byte offset in window (linear dest)
      int row = X >> 7;                  // px index in window
      int Xs = X ^ ((row & 7) << 4);     // source permutation = read permutation
      glds16(src + Xs, dstb + X);
    }
  };
  auto COMPUTE = [&](int buf, int ky) {
    const char* sb = (const char*)&sa[buf][0];
    __builtin_amdgcn_s_setprio(1);
#pragma unroll
    for (int kx = 0; kx < 3; ++kx) {
      const unsigned short* wk = wb_bf + (dsel * 9 + ky * 3 + kx) * 4096;
      int px0 = 16 + (kx - 1) * d + wid * 64;  // window-relative px, this wave
#pragma unroll
      for (int kc = 0; kc < 2; ++kc) {
        bf16x8 bfrag[4];
#pragma unroll
        for (int t = 0; t < 4; ++t)
          bfrag[t] = *(const bf16x8*)(wk + (t * 16 + m) * 64 + kc * 32 + q * 8);
#pragma unroll
        for (int mt = 0; mt < 4; ++mt) {
          int px = px0 + mt * 16 + m;
          int byteoff = px * 128 + ((kc * 64 + q * 16) ^ ((px & 7) << 4));
          bf16x8 afrag = *(const bf16x8*)(sb + byteoff);
#pragma unroll
          for (int t = 0; t < 4; ++t)
            acc[mt][t] = __builtin_amdgcn_mfma_f32_16x16x32_bf16(
                afrag, bfrag[t], acc[mt][t], 0, 0, 0);
        }
      }
    }
    __builtin_amdgcn_s_setprio(0);
  };

  STAGE(0, 0);
  __syncthreads();            // vmcnt(0) drain + barrier (buf0 ready)
  STAGE(1, 1);                // prefetch row1 while computing row0
  COMPUTE(0, 0);
  __syncthreads();            // buf1 ready; buf0 reads done
  STAGE(0, 2);                // prefetch row2 while computing row1
  COMPUTE(1, 1);
  __syncthreads();            // buf0 ready; buf1 reads done
  COMPUTE(0, 2);

  // epilogue: bias + lrelu, pack bf16 via LDS (stride 68: v3-proven 0-conflict)
  __syncthreads();            // all buf0 reads done before ep overwrite
  unsigned short* epb = &sa[0][0];  // ep[pix*68 + co], 34816 B
#pragma unroll
  for (int t = 0; t < 4; ++t) {
    float bi = bias[t * 16 + m];
#pragma unroll
    for (int mt = 0; mt < 4; ++mt)
#pragma unroll
      for (int r = 0; r < 4; ++r)  // D: col=co (m), row=q*4+r (pixel)
        epb[(wid * 64 + mt * 16 + q * 4 + r) * 68 + t * 16 + m] =
            f2bf(lrelu(acc[mt][t][r] + bi));
  }
  __syncthreads();
  {
    int qa = pos0 + tid;  // padded position of this thread's pixel
    int pr = qa / WP, pc = qa - pr * WP;
    if (pr >= 4 && pr < 164 && pc >= 4 && pc < 164) {
      int hw = (pr - 4) * W + (pc - 4);
      unsigned short* dst = r_bf + ((size_t)(b * HW + hw)) * 192 + dsel * 64;
      const unsigned short* s2 = epb + tid * 68;
#pragma unroll
      for (int c = 0; c < 8; ++c)
        *(uint4*)(dst + c * 8) = *(const uint4*)(s2 + c * 8);
    }
  }
}

// ---------------------------------------------------------------------------
// Kernel C: MFMA merge 192->64 (+bias+residual) then offset head 64->18.
// grid: B*HW/64 = 1600
// ---------------------------------------------------------------------------
__global__ __launch_bounds__(256) void k_merge_head_mfma(
    const unsigned short* __restrict__ r_bf, const float* __restrict__ off0,
    const unsigned short* __restrict__ arw_bf, const float* __restrict__ arb,
    const float* __restrict__ w02, const float* __restrict__ b02,
    float* __restrict__ offs) {
  __shared__ unsigned short sa[64 * 200];  // 25600 B; reused as float ep[64*65]
  int pos0 = blockIdx.x * 64;
  int b = pos0 / HW;
  int hw0 = pos0 - b * HW;
  int tid = threadIdx.x;
  const unsigned short* gsrc = r_bf + (size_t)(b * HW + hw0) * 192;
  for (int i = tid; i < 1536; i += 256) {
    int pos = i / 24, c8 = i - pos * 24;
    *(uint4*)(sa + pos * 200 + c8 * 8) = *(const uint4*)(gsrc + i * 8);
  }
  __syncthreads();
  int lane = tid & 63, wid = tid >> 6;
  int m = lane & 15, q = lane >> 4;
  f32x4 acc[4] = {};
#pragma unroll
  for (int kc = 0; kc < 6; ++kc) {
    bf16x8 bfrag = *(const bf16x8*)(arw_bf + (wid * 16 + m) * 192 + kc * 32 + q * 8);
#pragma unroll
    for (int mt = 0; mt < 4; ++mt) {
      bf16x8 afrag = *(const bf16x8*)(sa + (mt * 16 + m) * 200 + kc * 32 + q * 8);
      acc[mt] = __builtin_amdgcn_mfma_f32_16x16x32_bf16(afrag, bfrag, acc[mt],
                                                        0, 0, 0);
    }
  }
  __syncthreads();  // all afrag reads done before overwriting sa
  float* ep = (float*)sa;  // ep[pos*65 + co]
  int co = wid * 16 + m;
  float bi = arb[co];
  const float* resrow = off0 + (size_t)(b * 64 + co) * HW + hw0;
#pragma unroll
  for (int mt = 0; mt < 4; ++mt)
#pragma unroll
    for (int r = 0; r < 4; ++r) {
      int pos = mt * 16 + q * 4 + r;  // D: col=co, row=pos
      ep[pos * 65 + co] = acc[mt][r] + bi + resrow[pos];
    }
  __syncthreads();
  for (int i = tid; i < 1152; i += 256) {
    int t = i >> 6, p = i & 63;
    const float* w2 = w02 + t * 64;  // t wave-uniform -> s_loads
    float o = b02[t];
#pragma unroll 8
    for (int c = 0; c < 64; ++c) o += ep[p * 65 + c] * w2[c];
    offs[(b * 18 + t) * HW + hw0 + p] = o;
  }
}

// ---------------------------------------------------------------------------
// Kernel E v9: v8 skeleton (tap-paired LDS sampling, raw barriers, verified
// read paths) + COALESCED gather geometry from v2. Old role lane=px made
// every gather inst fan to 64 distinct cache lines (TA-request bound:
// 460K insts x 64 lines / 256 CU ~ 48us -- the 78.5us pin). New role:
// px = wid*16 + (lane&15), chunk q = lane>>4; per corner the 4 q-lanes of a
// px read two 16B chunks at q*16 and 64+q*16 -> 64B-contiguous quads ->
// 16 lines/inst (4x fewer TA requests). Same per-lane load/VALU count.
// LDS write puts chunk c at byte c*16 of row px with the same XOR involution
// the verified GEMM read expects (read side untouched).
// grid: 1600
// ---------------------------------------------------------------------------
__global__ __launch_bounds__(256) void k_deform_mfma(
    const unsigned short* __restrict__ x_bf, const float* __restrict__ offs,
    const unsigned short* __restrict__ wd_bf, const float* __restrict__ db,
    float* __restrict__ out) {
  __shared__ unsigned short sb[2][2][64 * 64];  // 2 bufs x 2 taps x 8 KB = 32 KB
  int blk = (blockIdx.x & 7) * 200 + (blockIdx.x >> 3);  // XCD slab swizzle
  int pos0 = blk * 64;
  int b = pos0 / HW;
  int hw0 = pos0 - b * HW;
  int tid = threadIdx.x;
  int lane = tid & 63, wid = tid >> 6;
  int m = lane & 15, q = lane >> 4;
  int hw = hw0 + wid * 16 + m;   // sampling pixel (4 q-lanes share one px)
  int h = hw / W, wv = hw - h * W;
  const unsigned short* xbase = x_bf + (size_t)b * HW * 64;
  const float* ob = offs + b * 18 * HW + hw;
  float offv[18];
#pragma unroll
  for (int j = 0; j < 18; ++j) offv[j] = ob[j * HW];
  f32x4 acc[4] = {};

  // gather (coalesced: chunks q and q+4 of this px's corner rows) + blend +
  // swizzled ds_write of tap k into dstbase
  auto SAMPLE = [&](int k, unsigned short* dstbase) {
    const int ky = k / 3, kx = k - ky * 3;
    float py = offv[2 * k] + (float)(h - 1 + ky);
    float pxf = offv[2 * k + 1] + (float)(wv - 1 + kx);
    float fy = floorf(py), fx = floorf(pxf);
    int iy0 = (int)fy, ix0 = (int)fx;
    float wy = py - fy, wx = pxf - fx;
    int iy1 = iy0 + 1, ix1 = ix0 + 1;
    float vy0 = (iy0 >= 0 && iy0 < H) ? 1.f : 0.f;
    float vy1 = (iy1 >= 0 && iy1 < H) ? 1.f : 0.f;
    float vx0 = (ix0 >= 0 && ix0 < W) ? 1.f : 0.f;
    float vx1 = (ix1 >= 0 && ix1 < W) ? 1.f : 0.f;
    int cy0 = min(max(iy0, 0), H - 1), cy1 = min(max(iy1, 0), H - 1);
    int cx0 = min(max(ix0, 0), W - 1), cx1 = min(max(ix1, 0), W - 1);
    float c00 = vy0 * vx0 * (1.f - wy) * (1.f - wx);
    float c01 = vy0 * vx1 * (1.f - wy) * wx;
    float c10 = vy1 * vx0 * wy * (1.f - wx);
    float c11 = vy1 * vx1 * wy * wx;
    // chunk q (ci q*8..+8) and chunk q+4 (ci 32+q*8..+8) of each corner row
    const unsigned short* p00 = xbase + (size_t)(cy0 * W + cx0) * 64 + q * 8;
    const unsigned short* p01 = xbase + (size_t)(cy0 * W + cx1) * 64 + q * 8;
    const unsigned short* p10 = xbase + (size_t)(cy1 * W + cx0) * 64 + q * 8;
    const unsigned short* p11 = xbase + (size_t)(cy1 * W + cx1) * 64 + q * 8;
    unsigned tw0[4], tw1[4];
#pragma unroll
    for (int c2 = 0; c2 < 2; ++c2) {
      bf16x8 v00 = *(const bf16x8*)(p00 + c2 * 32);
      bf16x8 v01 = *(const bf16x8*)(p01 + c2 * 32);
      bf16x8 v10 = *(const bf16x8*)(p10 + c2 * 32);
      bf16x8 v11 = *(const bf16x8*)(p11 + c2 * 32);
      unsigned* tw = c2 ? tw1 : tw0;
#pragma unroll
      for (int jj = 0; jj < 4; ++jj) {
        float s0 = c00 * bf2f(v00[2 * jj]) + c01 * bf2f(v01[2 * jj]) +
                   c10 * bf2f(v10[2 * jj]) + c11 * bf2f(v11[2 * jj]);
        float s1 = c00 * bf2f(v00[2 * jj + 1]) + c01 * bf2f(v01[2 * jj + 1]) +
                   c10 * bf2f(v10[2 * jj + 1]) + c11 * bf2f(v11[2 * jj + 1]);
        asm("v_cvt_pk_bf16_f32 %0, %1, %2" : "=v"(tw[jj]) : "v"(s0), "v"(s1));
      }
    }
    int row = wid * 16 + m;
    char* wbase = (char*)dstbase + row * 128;
    int sw = (row & 7) << 4;
    *(uint4*)(wbase + ((q * 16) ^ sw)) = *(const uint4*)&tw0[0];
    *(uint4*)(wbase + ((64 + q * 16) ^ sw)) = *(const uint4*)&tw1[0];
  };
  auto GEMM_TAP = [&](int k, const unsigned short* basep) {
#pragma unroll
    for (int kc = 0; kc < 2; ++kc) {
      bf16x8 bfrag =
          *(const bf16x8*)(wd_bf + (k * 64 + wid * 16 + m) * 64 + kc * 32 + q * 8);
#pragma unroll
      for (int mt = 0; mt < 4; ++mt) {
        int row = mt * 16 + m;
        int off = (kc * 64 + q * 16) ^ ((row & 7) << 4);  // same involution
        bf16x8 afrag = *(const bf16x8*)((const char*)basep + row * 128 + off);
        acc[mt] = __builtin_amdgcn_mfma_f32_16x16x32_bf16(afrag, bfrag, acc[mt],
                                                          0, 0, 0);
      }
    }
  };

#pragma unroll
  for (int r = 0; r < 4; ++r) {
    SAMPLE(2 * r, &sb[r & 1][0][0]);
    SAMPLE(2 * r + 1, &sb[r & 1][1][0]);
    __builtin_amdgcn_sched_barrier(0);
    asm volatile("s_waitcnt lgkmcnt(0)" ::: "memory");
    __builtin_amdgcn_s_barrier();
    __builtin_amdgcn_sched_barrier(0);
    __builtin_amdgcn_s_setprio(1);
    GEMM_TAP(2 * r, &sb[r & 1][0][0]);
    GEMM_TAP(2 * r + 1, &sb[r & 1][1][0]);
    __builtin_amdgcn_s_setprio(0);
  }
  // tap 8 (buf 0 half 0 -- last read two rounds back; round 3's barrier
  // separates those reads from these writes, same spacing as the loop)
  SAMPLE(8, &sb[0][0][0]);
  __builtin_amdgcn_sched_barrier(0);
  asm volatile("s_waitcnt lgkmcnt(0)" ::: "memory");
  __builtin_amdgcn_s_barrier();
  __builtin_amdgcn_sched_barrier(0);
  __builtin_amdgcn_s_setprio(1);
  GEMM_TAP(8, &sb[0][0][0]);
  __builtin_amdgcn_s_setprio(0);

  int co = wid * 16 + m;
  float bias = db[co];
  size_t orow = (size_t)(b * 64 + co) * HW + hw0;
#pragma unroll
  for (int mt = 0; mt < 4; ++mt)
#pragma unroll
    for (int r = 0; r < 4; ++r)
      out[orow + mt * 16 + q * 4 + r] = acc[mt][r] + bias;  // D: col=co, row=pos
}

// ---------------------------------------------------------------------------
extern "C" void kernel_launch(void* const* d_in, const int* in_sizes, int n_in,
                              void* d_out, int out_size, void* d_ws, size_t ws_size,
                              hipStream_t stream) {
  const float* aux = (const float*)d_in[0];
  const float* ref = (const float*)d_in[1];
  const float* w01 = (const float*)d_in[2];
  const float* b01 = (const float*)d_in[3];
  const float* a1w = (const float*)d_in[4];
  const float* a1b = (const float*)d_in[5];
  const float* a2w = (const float*)d_in[6];
  const float* a2b = (const float*)d_in[7];
  const float* a3w = (const float*)d_in[8];
  const float* a3b = (const float*)d_in[9];
  const float* arw = (const float*)d_in[10];
  const float* arb = (const float*)d_in[11];
  const float* w02 = (const float*)d_in[12];
  const float* b02 = (const float*)d_in[13];
  const float* dw  = (const float*)d_in[14];
  const float* db  = (const float*)d_in[15];
  float* out = (float*)d_out;

  float* off0 = (float*)d_ws;                        // [B,64,H,W] fp32
  float* offs = off0 + NELEM;                        // [B,18,H,W] fp32
  float* wt01 = offs + B * 18 * HW;                  // 8192 f32
  unsigned short* off0p = (unsigned short*)(wt01 + 8192);    // [B,PSTRIDE,64] bf16
  unsigned short* x_bf   = off0p + (size_t)B * PSTRIDE * 64; // [B,HW,64] bf16
  unsigned short* wb_bf  = x_bf + (size_t)NELEM;             // 110592 bf16
  unsigned short* wd_bf  = wb_bf + 110592;                   // 36864 bf16
  unsigned short* arw_bf = wd_bf + 36864;                    // 12288 bf16
  unsigned short* r_bf   = arw_bf + 12288;           // [B,HW,192] bf16

  k_transform<<<656, 256, 0, stream>>>(w01, dw, arw, a1w, a2w, a3w,
                                       wt01, wb_bf, wd_bf, arw_bf, off0p);
  k_conv1x1_in<<<B * HW / 64, 256, 0, stream>>>(aux, ref, wt01, b01, off0,
                                                off0p, x_bf);
  k_aspp3_mfma<<<1332, 256, 0, stream>>>(off0p, wb_bf, a1b, a2b, a3b, r_bf);
  k_merge_head_mfma<<<B * HW / 64, 256, 0, stream>>>(
      r_bf, off0, arw_bf, arb, w02, b02, offs);
  k_deform_mfma<<<B * HW / 64, 256, 0, stream>>>(x_bf, offs, wd_bf, db, out);
}

// Round 14
// 312.289 us; speedup vs baseline: 1.0526x; 1.0271x over previous
//
#include <hip/hip_runtime.h>
#include <math.h>

static constexpr int B = 4, H = 160, W = 160;
static constexpr int HW = H * W;          // 25600
static constexpr int CHW = 64 * HW;       // 1638400
static constexpr int NELEM = B * CHW;     // 6553600

// padded grid for aspp GEMM view: 168x168 (halo 4) + guard slack
static constexpr int WP = 168;
static constexpr int HP = 168;
static constexpr int PHW = WP * HP;       // 28224
static constexpr int PGUARD = 704;        // front guard (>= 4*168+16)
static constexpr int PSTRIDE = 30720;     // per-b px stride
static constexpr int IMGOFS = PGUARD + 4 * WP + 4;  // = 1380, padded idx of (0,0)

typedef short bf16x8 __attribute__((ext_vector_type(8)));
typedef float f32x4 __attribute__((ext_vector_type(4)));

__device__ __forceinline__ float lrelu(float v) { return v >= 0.f ? v : 0.1f * v; }

__device__ __forceinline__ unsigned short f2bf(float f) {
  unsigned u = __float_as_uint(f);
  return (unsigned short)((u + 0x7FFFu + ((u >> 16) & 1u)) >> 16);  // RNE
}
__device__ __forceinline__ float bf2f(short u) {
  return __uint_as_float(((unsigned)(unsigned short)u) << 16);
}

__device__ __forceinline__ void glds16(const void* g, void* l) {
  __builtin_amdgcn_global_load_lds(
      (const __attribute__((address_space(1))) void*)g,
      (__attribute__((address_space(3))) void*)l, 16, 0, 0);
}

// ---------------------------------------------------------------------------
// Weight transforms + zero-fill of the padded input buffer (margins must be 0).
//   w01_bf[co*128+ci] = bf16(w01[co*128+ci])   (native layout, 8192 bf16)
// ---------------------------------------------------------------------------
__global__ __launch_bounds__(256) void k_transform(
    const float* __restrict__ w01, const float* __restrict__ dw,
    const float* __restrict__ arw, const float* __restrict__ a1w,
    const float* __restrict__ a2w, const float* __restrict__ a3w,
    unsigned short* __restrict__ w01_bf, unsigned short* __restrict__ wb_bf,
    unsigned short* __restrict__ wd_bf, unsigned short* __restrict__ arw_bf,
    unsigned short* __restrict__ off0p) {
  int i = blockIdx.x * 256 + threadIdx.x;  // 0 .. 167935
  uint4* zp = (uint4*)off0p;
#pragma unroll
  for (int j = 0; j < 6; ++j) {
    unsigned u = (unsigned)i + (unsigned)j * 167936u;
    if (u < 983040u) zp[u] = make_uint4(0u, 0u, 0u, 0u);
  }
  if (i < 8192) {
    w01_bf[i] = f2bf(w01[i]);  // [co][ci] native
  } else if (i < 118784) {
    int j = i - 8192;
    int ci = j & 63, co = (j >> 6) & 63;
    int kk = j >> 12;              // dsel*9 + k, 0..26
    int dsel = kk / 9; kk -= dsel * 9;
    const float* src = dsel == 0 ? a1w : dsel == 1 ? a2w : a3w;
    wb_bf[j] = f2bf(src[(co * 64 + ci) * 9 + kk]);
  } else if (i < 155648) {
    int j = i - 118784;
    int ci = j & 63, co = (j >> 6) & 63, k = j >> 12;  // k 0..8
    wd_bf[j] = f2bf(dw[(co * 64 + ci) * 9 + k]);
  } else if (i < 167936) {
    int j = i - 155648;
    arw_bf[j] = f2bf(arw[j]);  // already [o][cp]
  }
}

// ---------------------------------------------------------------------------
// Kernel A v2: 1x1 conv concat(aux,ref) 128->64 via MFMA.
// Old version: 128ci x 16co scalar FMA loop = 2048 VALU FMA/thread
// (~42us VALU-bound, G10 violation). Now: stage [px][128ci] bf16 rows in LDS
// (256B rows, XOR swz both sides; staging loads coalesced 256B since cg=wid),
// wave = 16px x 64co x K=128 -> 16 MFMAs. Epilogue: fp32 ep2[px*65+co] in
// LDS -> coalesced channel-major out + bf16 off0p; x_bf = aux half of the
// staged A-rows (free). grid: B*HW/64 = 1600
// ---------------------------------------------------------------------------
__global__ __launch_bounds__(256) void k_conv1x1_in(
    const float* __restrict__ aux, const float* __restrict__ ref,
    const unsigned short* __restrict__ w01_bf, const float* __restrict__ b01,
    float* __restrict__ out, unsigned short* __restrict__ off0p,
    unsigned short* __restrict__ x_bf) {
  __shared__ unsigned short sA[64 * 128];  // 16 KB, 256B rows, XOR swz
  __shared__ float ep2[64 * 65];           // 16.6 KB fp32 repack
  int pos0 = blockIdx.x * 64;
  int b = pos0 / HW;
  int hw0 = pos0 - b * HW;
  int tid = threadIdx.x;
  int lane = tid & 63, wid = tid >> 6;
  int m = lane & 15, q = lane >> 4;

  // stage: thread (cg=wid, px=lane) packs 32 channels of its pixel
  {
    int px = lane, cg = wid;
    int hw = hw0 + px;
    const float* srcb = (cg < 2)
        ? (aux + (size_t)b * CHW + (size_t)(cg * 32) * HW)
        : (ref + (size_t)b * CHW + (size_t)((cg - 2) * 32) * HW);
    unsigned tw[16];
#pragma unroll
    for (int j = 0; j < 16; ++j) {
      float f0 = srcb[(size_t)(2 * j) * HW + hw];
      float f1 = srcb[(size_t)(2 * j + 1) * HW + hw];
      asm("v_cvt_pk_bf16_f32 %0, %1, %2" : "=v"(tw[j]) : "v"(f0), "v"(f1));
    }
    char* rowp = (char*)sA + px * 256;
    int sw = (px & 7) << 4;
#pragma unroll
    for (int s = 0; s < 4; ++s)
      *(uint4*)(rowp + ((cg * 64 + s * 16) ^ sw)) = ((const uint4*)tw)[s];
  }
  __syncthreads();

  // x_bf: aux half (ci 0..63) of each row, de-swizzled copy (32B/thread)
  {
    int px = tid >> 2, hq = tid & 3;
    int hw = hw0 + px;
    const char* rp = (const char*)sA + px * 256;
    int sw = (px & 7) << 4;
    unsigned short* xdst = x_bf + ((size_t)(b * HW + hw)) * 64 + hq * 16;
    *(uint4*)xdst = *(const uint4*)(rp + ((hq * 32) ^ sw));
    *(uint4*)(xdst + 8) = *(const uint4*)(rp + ((hq * 32 + 16) ^ sw));
  }

  // MFMA: wave = 16 px x 64 co, K=128 -> 16 MFMAs
  f32x4 acc[4] = {};
  {
    const char* arp = (const char*)sA + (wid * 16 + m) * 256;
    int asw = (m & 7) << 4;  // (wid*16+m)&7 == m&7
#pragma unroll
    for (int kc = 0; kc < 4; ++kc) {
      bf16x8 afrag = *(const bf16x8*)(arp + ((kc * 64 + q * 16) ^ asw));
#pragma unroll
      for (int t = 0; t < 4; ++t) {
        bf16x8 bfrag =
            *(const bf16x8*)(w01_bf + (t * 16 + m) * 128 + kc * 32 + q * 8);
        acc[t] = __builtin_amdgcn_mfma_f32_16x16x32_bf16(afrag, bfrag, acc[t],
                                                         0, 0, 0);
      }
    }
  }

  // bias + lrelu -> fp32 repack (D: col=co=t*16+m, row=px=wid*16+q*4+r)
#pragma unroll
  for (int t = 0; t < 4; ++t) {
    int co = t * 16 + m;
    float bi = b01[co];
#pragma unroll
    for (int r = 0; r < 4; ++r)
      ep2[(wid * 16 + q * 4 + r) * 65 + co] = lrelu(acc[t][r] + bi);
  }
  __syncthreads();

  // out fp32 channel-major, coalesced: thread (cg=wid co-group, px=lane)
  {
    int px = lane, cg = wid;
#pragma unroll
    for (int j = 0; j < 16; ++j)
      out[(size_t)(b * 64 + cg * 16 + j) * HW + hw0 + px] =
          ep2[px * 65 + cg * 16 + j];
  }
  // off0p bf16 pos-major (padded), 16 ci per thread
  {
    int px = tid >> 2, c4 = tid & 3;
    int hw = hw0 + px;
    int h = hw / W, w = hw - h * W;
    unsigned short* dst =
        off0p + ((size_t)b * PSTRIDE + IMGOFS + h * WP + w) * 64 + c4 * 16;
    const float* src = ep2 + px * 65 + c4 * 16;
    unsigned short tb[16];
#pragma unroll
    for (int j = 0; j < 16; ++j) tb[j] = f2bf(src[j]);
    *(uint4*)dst = *(const uint4*)&tb[0];
    *(uint4*)(dst + 8) = *(const uint4*)&tb[8];
  }
}

// ---------------------------------------------------------------------------
// Kernel B v5: padded-GEMM aspp, row-union staging + 2-phase pipeline + swz.
// (R11 best-measured version: __syncthreads skeleton + T5 setprio)
// ---------------------------------------------------------------------------
__global__ __launch_bounds__(256) void k_aspp3_mfma(
    const unsigned short* __restrict__ off0p,
    const unsigned short* __restrict__ wb_bf,
    const float* __restrict__ a1b, const float* __restrict__ a2b,
    const float* __restrict__ a3b, unsigned short* __restrict__ r_bf) {
  __shared__ unsigned short sa[2][288 * 64];  // 2 x 36864 B
  int tid = threadIdx.x;
  int lane = tid & 63, wid = tid >> 6;
  int m = lane & 15, q = lane >> 4;

  // bijective XCD swizzle for nwg=1332 (q=166, r=4)
  int p0 = blockIdx.x;
  int xcd = p0 & 7, ii = p0 >> 3;
  int base = xcd < 4 ? xcd * 167 : 668 + (xcd - 4) * 166;
  int lid = base + ii;
  int dsel = lid % 3;
  int tj = lid / 3;
  int b = tj / 111;
  int tile = tj - b * 111;
  int pos0 = tile * 256;
  const int d = 1 << dsel;
  const unsigned short* pb = off0p + (size_t)b * PSTRIDE * 64;
  const float* bias = dsel == 0 ? a1b : dsel == 1 ? a2b : a3b;

  f32x4 acc[4][4] = {};

  auto STAGE = [&](int buf, int ky) {
    const char* src =
        (const char*)(pb + (size_t)(PGUARD + pos0 + (ky - 1) * d * WP - 16) * 64);
    char* dstb = (char*)&sa[buf][0];
#pragma unroll
    for (int r = 0; r < 9; ++r) {
      int X = r * 4096 + tid * 16;       // byte offset in window (linear dest)
      int row = X >> 7;                  // px index in window
      int Xs = X ^ ((row & 7) << 4);     // source permutation = read permutation
      glds16(src + Xs, dstb + X);
    }
  };
  auto COMPUTE = [&](int buf, int ky) {
    const char* sb = (const char*)&sa[buf][0];
    __builtin_amdgcn_s_setprio(1);
#pragma unroll
    for (int kx = 0; kx < 3; ++kx) {
      const unsigned short* wk = wb_bf + (dsel * 9 + ky * 3 + kx) * 4096;
      int px0 = 16 + (kx - 1) * d + wid * 64;  // window-relative px, this wave
#pragma unroll
      for (int kc = 0; kc < 2; ++kc) {
        bf16x8 bfrag[4];
#pragma unroll
        for (int t = 0; t < 4; ++t)
          bfrag[t] = *(const bf16x8*)(wk + (t * 16 + m) * 64 + kc * 32 + q * 8);
#pragma unroll
        for (int mt = 0; mt < 4; ++mt) {
          int px = px0 + mt * 16 + m;
          int byteoff = px * 128 + ((kc * 64 + q * 16) ^ ((px & 7) << 4));
          bf16x8 afrag = *(const bf16x8*)(sb + byteoff);
#pragma unroll
          for (int t = 0; t < 4; ++t)
            acc[mt][t] = __builtin_amdgcn_mfma_f32_16x16x32_bf16(
                afrag, bfrag[t], acc[mt][t], 0, 0, 0);
        }
      }
    }
    __builtin_amdgcn_s_setprio(0);
  };

  STAGE(0, 0);
  __syncthreads();            // vmcnt(0) drain + barrier (buf0 ready)
  STAGE(1, 1);                // prefetch row1 while computing row0
  COMPUTE(0, 0);
  __syncthreads();            // buf1 ready; buf0 reads done
  STAGE(0, 2);                // prefetch row2 while computing row1
  COMPUTE(1, 1);
  __syncthreads();            // buf0 ready; buf1 reads done
  COMPUTE(0, 2);

  // epilogue: bias + lrelu, pack bf16 via LDS (stride 68: v3-proven 0-conflict)
  __syncthreads();            // all buf0 reads done before ep overwrite
  unsigned short* epb = &sa[0][0];  // ep[pix*68 + co], 34816 B
#pragma unroll
  for (int t = 0; t < 4; ++t) {
    float bi = bias[t * 16 + m];
#pragma unroll
    for (int mt = 0; mt < 4; ++mt)
#pragma unroll
      for (int r = 0; r < 4; ++r)  // D: col=co (m), row=q*4+r (pixel)
        epb[(wid * 64 + mt * 16 + q * 4 + r) * 68 + t * 16 + m] =
            f2bf(lrelu(acc[mt][t][r] + bi));
  }
  __syncthreads();
  {
    int qa = pos0 + tid;  // padded position of this thread's pixel
    int pr = qa / WP, pc = qa - pr * WP;
    if (pr >= 4 && pr < 164 && pc >= 4 && pc < 164) {
      int hw = (pr - 4) * W + (pc - 4);
      unsigned short* dst = r_bf + ((size_t)(b * HW + hw)) * 192 + dsel * 64;
      const unsigned short* s2 = epb + tid * 68;
#pragma unroll
      for (int c = 0; c < 8; ++c)
        *(uint4*)(dst + c * 8) = *(const uint4*)(s2 + c * 8);
    }
  }
}

// ---------------------------------------------------------------------------
// Kernel C: MFMA merge 192->64 (+bias+residual) then offset head 64->18.
// grid: B*HW/64 = 1600
// ---------------------------------------------------------------------------
__global__ __launch_bounds__(256) void k_merge_head_mfma(
    const unsigned short* __restrict__ r_bf, const float* __restrict__ off0,
    const unsigned short* __restrict__ arw_bf, const float* __restrict__ arb,
    const float* __restrict__ w02, const float* __restrict__ b02,
    float* __restrict__ offs) {
  __shared__ unsigned short sa[64 * 200];  // 25600 B; reused as float ep[64*65]
  int pos0 = blockIdx.x * 64;
  int b = pos0 / HW;
  int hw0 = pos0 - b * HW;
  int tid = threadIdx.x;
  const unsigned short* gsrc = r_bf + (size_t)(b * HW + hw0) * 192;
  for (int i = tid; i < 1536; i += 256) {
    int pos = i / 24, c8 = i - pos * 24;
    *(uint4*)(sa + pos * 200 + c8 * 8) = *(const uint4*)(gsrc + i * 8);
  }
  __syncthreads();
  int lane = tid & 63, wid = tid >> 6;
  int m = lane & 15, q = lane >> 4;
  f32x4 acc[4] = {};
#pragma unroll
  for (int kc = 0; kc < 6; ++kc) {
    bf16x8 bfrag = *(const bf16x8*)(arw_bf + (wid * 16 + m) * 192 + kc * 32 + q * 8);
#pragma unroll
    for (int mt = 0; mt < 4; ++mt) {
      bf16x8 afrag = *(const bf16x8*)(sa + (mt * 16 + m) * 200 + kc * 32 + q * 8);
      acc[mt] = __builtin_amdgcn_mfma_f32_16x16x32_bf16(afrag, bfrag, acc[mt],
                                                        0, 0, 0);
    }
  }
  __syncthreads();  // all afrag reads done before overwriting sa
  float* ep = (float*)sa;  // ep[pos*65 + co]
  int co = wid * 16 + m;
  float bi = arb[co];
  const float* resrow = off0 + (size_t)(b * 64 + co) * HW + hw0;
#pragma unroll
  for (int mt = 0; mt < 4; ++mt)
#pragma unroll
    for (int r = 0; r < 4; ++r) {
      int pos = mt * 16 + q * 4 + r;  // D: col=co, row=pos
      ep[pos * 65 + co] = acc[mt][r] + bi + resrow[pos];
    }
  __syncthreads();
  for (int i = tid; i < 1152; i += 256) {
    int t = i >> 6, p = i & 63;
    const float* w2 = w02 + t * 64;  // t wave-uniform -> s_loads
    float o = b02[t];
#pragma unroll 8
    for (int c = 0; c < 64; ++c) o += ep[p * 65 + c] * w2[c];
    offs[(b * 18 + t) * HW + hw0 + p] = o;
  }
}

// ---------------------------------------------------------------------------
// Kernel E v9: tap-paired LDS sampling + coalesced gather geometry.
// (R13 passing version, 75.3 us, unchanged) grid: 1600
// ---------------------------------------------------------------------------
__global__ __launch_bounds__(256) void k_deform_mfma(
    const unsigned short* __restrict__ x_bf, const float* __restrict__ offs,
    const unsigned short* __restrict__ wd_bf, const float* __restrict__ db,
    float* __restrict__ out) {
  __shared__ unsigned short sb[2][2][64 * 64];  // 2 bufs x 2 taps x 8 KB = 32 KB
  int blk = (blockIdx.x & 7) * 200 + (blockIdx.x >> 3);  // XCD slab swizzle
  int pos0 = blk * 64;
  int b = pos0 / HW;
  int hw0 = pos0 - b * HW;
  int tid = threadIdx.x;
  int lane = tid & 63, wid = tid >> 6;
  int m = lane & 15, q = lane >> 4;
  int hw = hw0 + wid * 16 + m;   // sampling pixel (4 q-lanes share one px)
  int h = hw / W, wv = hw - h * W;
  const unsigned short* xbase = x_bf + (size_t)b * HW * 64;
  const float* ob = offs + b * 18 * HW + hw;
  float offv[18];
#pragma unroll
  for (int j = 0; j < 18; ++j) offv[j] = ob[j * HW];
  f32x4 acc[4] = {};

  auto SAMPLE = [&](int k, unsigned short* dstbase) {
    const int ky = k / 3, kx = k - ky * 3;
    float py = offv[2 * k] + (float)(h - 1 + ky);
    float pxf = offv[2 * k + 1] + (float)(wv - 1 + kx);
    float fy = floorf(py), fx = floorf(pxf);
    int iy0 = (int)fy, ix0 = (int)fx;
    float wy = py - fy, wx = pxf - fx;
    int iy1 = iy0 + 1, ix1 = ix0 + 1;
    float vy0 = (iy0 >= 0 && iy0 < H) ? 1.f : 0.f;
    float vy1 = (iy1 >= 0 && iy1 < H) ? 1.f : 0.f;
    float vx0 = (ix0 >= 0 && ix0 < W) ? 1.f : 0.f;
    float vx1 = (ix1 >= 0 && ix1 < W) ? 1.f : 0.f;
    int cy0 = min(max(iy0, 0), H - 1), cy1 = min(max(iy1, 0), H - 1);
    int cx0 = min(max(ix0, 0), W - 1), cx1 = min(max(ix1, 0), W - 1);
    float c00 = vy0 * vx0 * (1.f - wy) * (1.f - wx);
    float c01 = vy0 * vx1 * (1.f - wy) * wx;
    float c10 = vy1 * vx0 * wy * (1.f - wx);
    float c11 = vy1 * vx1 * wy * wx;
    const unsigned short* p00 = xbase + (size_t)(cy0 * W + cx0) * 64 + q * 8;
    const unsigned short* p01 = xbase + (size_t)(cy0 * W + cx1) * 64 + q * 8;
    const unsigned short* p10 = xbase + (size_t)(cy1 * W + cx0) * 64 + q * 8;
    const unsigned short* p11 = xbase + (size_t)(cy1 * W + cx1) * 64 + q * 8;
    unsigned tw0[4], tw1[4];
#pragma unroll
    for (int c2 = 0; c2 < 2; ++c2) {
      bf16x8 v00 = *(const bf16x8*)(p00 + c2 * 32);
      bf16x8 v01 = *(const bf16x8*)(p01 + c2 * 32);
      bf16x8 v10 = *(const bf16x8*)(p10 + c2 * 32);
      bf16x8 v11 = *(const bf16x8*)(p11 + c2 * 32);
      unsigned* tw = c2 ? tw1 : tw0;
#pragma unroll
      for (int jj = 0; jj < 4; ++jj) {
        float s0 = c00 * bf2f(v00[2 * jj]) + c01 * bf2f(v01[2 * jj]) +
                   c10 * bf2f(v10[2 * jj]) + c11 * bf2f(v11[2 * jj]);
        float s1 = c00 * bf2f(v00[2 * jj + 1]) + c01 * bf2f(v01[2 * jj + 1]) +
                   c10 * bf2f(v10[2 * jj + 1]) + c11 * bf2f(v11[2 * jj + 1]);
        asm("v_cvt_pk_bf16_f32 %0, %1, %2" : "=v"(tw[jj]) : "v"(s0), "v"(s1));
      }
    }
    int row = wid * 16 + m;
    char* wbase = (char*)dstbase + row * 128;
    int sw = (row & 7) << 4;
    *(uint4*)(wbase + ((q * 16) ^ sw)) = *(const uint4*)&tw0[0];
    *(uint4*)(wbase + ((64 + q * 16) ^ sw)) = *(const uint4*)&tw1[0];
  };
  auto GEMM_TAP = [&](int k, const unsigned short* basep) {
#pragma unroll
    for (int kc = 0; kc < 2; ++kc) {
      bf16x8 bfrag =
          *(const bf16x8*)(wd_bf + (k * 64 + wid * 16 + m) * 64 + kc * 32 + q * 8);
#pragma unroll
      for (int mt = 0; mt < 4; ++mt) {
        int row = mt * 16 + m;
        int off = (kc * 64 + q * 16) ^ ((row & 7) << 4);  // same involution
        bf16x8 afrag = *(const bf16x8*)((const char*)basep + row * 128 + off);
        acc[mt] = __builtin_amdgcn_mfma_f32_16x16x32_bf16(afrag, bfrag, acc[mt],
                                                          0, 0, 0);
      }
    }
  };

#pragma unroll
  for (int r = 0; r < 4; ++r) {
    SAMPLE(2 * r, &sb[r & 1][0][0]);
    SAMPLE(2 * r + 1, &sb[r & 1][1][0]);
    __builtin_amdgcn_sched_barrier(0);
    asm volatile("s_waitcnt lgkmcnt(0)" ::: "memory");
    __builtin_amdgcn_s_barrier();
    __builtin_amdgcn_sched_barrier(0);
    __builtin_amdgcn_s_setprio(1);
    GEMM_TAP(2 * r, &sb[r & 1][0][0]);
    GEMM_TAP(2 * r + 1, &sb[r & 1][1][0]);
    __builtin_amdgcn_s_setprio(0);
  }
  SAMPLE(8, &sb[0][0][0]);
  __builtin_amdgcn_sched_barrier(0);
  asm volatile("s_waitcnt lgkmcnt(0)" ::: "memory");
  __builtin_amdgcn_s_barrier();
  __builtin_amdgcn_sched_barrier(0);
  __builtin_amdgcn_s_setprio(1);
  GEMM_TAP(8, &sb[0][0][0]);
  __builtin_amdgcn_s_setprio(0);

  int co = wid * 16 + m;
  float bias = db[co];
  size_t orow = (size_t)(b * 64 + co) * HW + hw0;
#pragma unroll
  for (int mt = 0; mt < 4; ++mt)
#pragma unroll
    for (int r = 0; r < 4; ++r)
      out[orow + mt * 16 + q * 4 + r] = acc[mt][r] + bias;  // D: col=co, row=pos
}

// ---------------------------------------------------------------------------
extern "C" void kernel_launch(void* const* d_in, const int* in_sizes, int n_in,
                              void* d_out, int out_size, void* d_ws, size_t ws_size,
                              hipStream_t stream) {
  const float* aux = (const float*)d_in[0];
  const float* ref = (const float*)d_in[1];
  const float* w01 = (const float*)d_in[2];
  const float* b01 = (const float*)d_in[3];
  const float* a1w = (const float*)d_in[4];
  const float* a1b = (const float*)d_in[5];
  const float* a2w = (const float*)d_in[6];
  const float* a2b = (const float*)d_in[7];
  const float* a3w = (const float*)d_in[8];
  const float* a3b = (const float*)d_in[9];
  const float* arw = (const float*)d_in[10];
  const float* arb = (const float*)d_in[11];
  const float* w02 = (const float*)d_in[12];
  const float* b02 = (const float*)d_in[13];
  const float* dw  = (const float*)d_in[14];
  const float* db  = (const float*)d_in[15];
  float* out = (float*)d_out;

  float* off0 = (float*)d_ws;                        // [B,64,H,W] fp32
  float* offs = off0 + NELEM;                        // [B,18,H,W] fp32
  float* wslot = offs + B * 18 * HW;                 // 8192 f32 slot
  unsigned short* w01_bf = (unsigned short*)wslot;   // 8192 bf16 (in slot)
  unsigned short* off0p = (unsigned short*)(wslot + 8192);   // [B,PSTRIDE,64] bf16
  unsigned short* x_bf   = off0p + (size_t)B * PSTRIDE * 64; // [B,HW,64] bf16
  unsigned short* wb_bf  = x_bf + (size_t)NELEM;             // 110592 bf16
  unsigned short* wd_bf  = wb_bf + 110592;                   // 36864 bf16
  unsigned short* arw_bf = wd_bf + 36864;                    // 12288 bf16
  unsigned short* r_bf   = arw_bf + 12288;           // [B,HW,192] bf16

  k_transform<<<656, 256, 0, stream>>>(w01, dw, arw, a1w, a2w, a3w,
                                       w01_bf, wb_bf, wd_bf, arw_bf, off0p);
  k_conv1x1_in<<<B * HW / 64, 256, 0, stream>>>(aux, ref, w01_bf, b01, off0,
                                                off0p, x_bf);
  k_aspp3_mfma<<<1332, 256, 0, stream>>>(off0p, wb_bf, a1b, a2b, a3b, r_bf);
  k_merge_head_mfma<<<B * HW / 64, 256, 0, stream>>>(
      r_bf, off0, arw_bf, arb, w02, b02, offs);
  k_deform_mfma<<<B * HW / 64, 256, 0, stream>>>(x_bf, offs, wd_bf, db, out);
}